// Round 8
// baseline (5569.267 us; speedup 1.0000x reference)
//
#include <hip/hip_runtime.h>
#include <hip/hip_fp16.h>

// Problem constants
#define TT 2048
#define II 1739
#define HN 256
#define H3 768
#define L2E 1.44269504088896f

typedef _Float16 h2 __attribute__((ext_vector_type(2)));

__device__ __forceinline__ float fdot2(h2 a, h2 b, float c) {
#if defined(__has_builtin)
#if __has_builtin(__builtin_amdgcn_fdot2)
  return __builtin_amdgcn_fdot2(a, b, c, false);
#else
  return fmaf((float)a[0], (float)b[0], fmaf((float)a[1], (float)b[1], c));
#endif
#else
  return fmaf((float)a[0], (float)b[0], fmaf((float)a[1], (float)b[1], c));
#endif
}

__device__ __forceinline__ float fast_exp2(float x) {
#if defined(__has_builtin)
#if __has_builtin(__builtin_amdgcn_exp2f)
  return __builtin_amdgcn_exp2f(x);
#else
  return exp2f(x);
#endif
#else
  return exp2f(x);
#endif
}

__device__ __forceinline__ float fast_rcp(float x) {
#if defined(__has_builtin)
#if __has_builtin(__builtin_amdgcn_rcpf)
  return __builtin_amdgcn_rcpf(x);
#else
  return 1.f / x;
#endif
#else
  return 1.f / x;
#endif
}

template <int CTRL>
__device__ __forceinline__ float dpp_qperm(float v) {
  int r = __builtin_amdgcn_update_dpp(0, __builtin_bit_cast(int, v), CTRL, 0xF, 0xF, true);
  return __builtin_bit_cast(float, r);
}

// C[M,N] = ((A[M,K] @ B[N,K]^T) + bias1[n] + (n < b2lim ? bias2[n] : 0)) * (n < slim ? s_lo : s_hi)
// 64x64 tile, 256 threads, 4x4 micro-tile per thread.
__global__ __launch_bounds__(256) void gemm_abt(
    const float* __restrict__ A, int M, int K,
    const float* __restrict__ B, int N,
    const float* __restrict__ bias1, const float* __restrict__ bias2, int b2lim,
    float s_lo, float s_hi, int slim,
    float* __restrict__ C) {
  __shared__ float As[16][64];
  __shared__ float Bs[16][64];
  const int tid = threadIdx.x;
  const int m0 = blockIdx.y * 64, n0 = blockIdx.x * 64;
  const int lr = tid >> 2;        // 0..63  (row within tile for loads)
  const int lk = (tid & 3) * 4;   // 0,4,8,12
  const int cx = tid & 15, cy = tid >> 4;
  float acc[4][4] = {};

  for (int k0 = 0; k0 < K; k0 += 16) {
#pragma unroll
    for (int i = 0; i < 4; ++i) {
      int k = k0 + lk + i;
      As[lk + i][lr] = (k < K) ? A[(size_t)(m0 + lr) * K + k] : 0.f;
      int bn = n0 + lr;
      Bs[lk + i][lr] = (k < K && bn < N) ? B[(size_t)bn * K + k] : 0.f;
    }
    __syncthreads();
#pragma unroll
    for (int k = 0; k < 16; ++k) {
      float4 av = *(const float4*)&As[k][cy * 4];
      float4 bv = *(const float4*)&Bs[k][cx * 4];
      const float aa[4] = {av.x, av.y, av.z, av.w};
      const float bb[4] = {bv.x, bv.y, bv.z, bv.w};
#pragma unroll
      for (int i = 0; i < 4; ++i)
#pragma unroll
        for (int j = 0; j < 4; ++j) acc[i][j] = fmaf(aa[i], bb[j], acc[i][j]);
    }
    __syncthreads();
  }
#pragma unroll
  for (int i = 0; i < 4; ++i) {
    int m = m0 + cy * 4 + i;
#pragma unroll
    for (int j = 0; j < 4; ++j) {
      int n = n0 + cx * 4 + j;
      if (n < N) {
        float b = bias1 ? bias1[n] : 0.f;
        if (bias2 && n < b2lim) b += bias2[n];
        float s = (n < slim) ? s_lo : s_hi;
        C[(size_t)m * N + n] = (acc[i][j] + b) * s;
      }
    }
  }
}

// Sequential GRU scan on a single CU (1 block, 512 threads = 8 waves).
//
// Diagnosis locked in over rounds 0-7: the kernel is VALU-ISSUE-bound at
// ~2150 cy/SIMD/step vs a ~1020-cy hand count. The per-thread weight
// footprint (192 dwords, invariant = 98304 weight-dwords / threads) always
// exceeds the arch-VGPR grant (~88 free of 128); the overflow is
// AGPR-resident, and v_dot2 (VOP3P) cannot source AGPRs -> ~1
// v_accvgpr_read per fdot2 on the overflow fraction = the constant ~2x
// VALU inflation. Attributes/thread-count/MFMA all failed to remove it.
//
// THIS ROUND: hand-spill the overflow to LDS (we use 1.5 KB of 160 KB!).
// Split each thread's 192 weight-dwords: 120 in registers (fits under the
// arch grant with the ~35-dword working set) + 72 in LDS (144 KB total).
// LDS weight reads issue on the LDS pipe, not the VALU pipe -> the tax
// becomes free bandwidth that overlaps the fdot2 stream.
//
// LDS weight layout (lane-major, conflict-free by construction): wave w,
// b128-slot s (= row*3 + j, 18 per thread), lane l ->
//   dword addr = 320 + w*4608 + s*256 + l*4
// A wave's ds_read_b128 at slot s covers 1024 contiguous bytes -> each
// 16-lane group spans all 32 banks exactly once. Same pattern for the
// prologue ds_write_b128.
//
// Everything else = round 4 exactly (best verified: 2140 us/scan,
// bit-identical accumulation order, same gate math, one __syncthreads
// per step, double-buffered f16 h at chunk-stride 40).
__global__ __launch_bounds__(512) void gru_seq(
    const float* __restrict__ xp,      // [T, 768], pre-scaled by L2E/2L2E
    const float* __restrict__ Whh,     // [768, 256]
    const float* __restrict__ bhh,     // [768]
    const float* __restrict__ h0,      // [256] or nullptr (zeros)
    float* __restrict__ hs_out,        // [T, 256] or nullptr
    float* __restrict__ hT_out) {      // [256] or nullptr
  extern __shared__ __align__(16) uint lds[];
  uint* hlds = lds;          // [2][160] dwords: double-buffered f16 h
  uint* wlds = lds + 320;    // [8][18][256] dwords: LDS-resident weights

  const int tid = threadIdx.x;
  const int lane = tid & 63;
  const int wv = tid >> 6;              // 0..7
  const int kc = lane & 3;              // k-chunk [64*kc, 64*kc+64)
  const int q = wv * 16 + (lane >> 2);  // 0..127; units 2q, 2q+1
  const int u0 = 2 * q;

  // Per-thread weight pointers into the lane-major LDS region.
  uint* wl = wlds + wv * 4608 + lane * 4;

  // Register-resident weights: pairs 0..19 (k 0..39 of this thread's
  // 64-k chunk) for each of the 6 owned gate rows. 120 dwords.
  h2 wreg[6][20];
#pragma unroll
  for (int uu = 0; uu < 2; ++uu) {
#pragma unroll
    for (int gg = 0; gg < 3; ++gg) {
      const float sc = (gg == 2) ? (2.f * L2E) : L2E;
      const float* wr = Whh + (size_t)(u0 + uu + gg * HN) * HN + kc * 64;
      const int i = uu * 3 + gg;
#pragma unroll
      for (int p = 0; p < 20; ++p) {
        float2 f = *(const float2*)(wr + 2 * p);
        wreg[i][p] = h2{(_Float16)(f.x * sc), (_Float16)(f.y * sc)};
      }
      // LDS-resident weights: pairs 20..31 (k 40..63), 3 b128 slots.
#pragma unroll
      for (int j = 0; j < 3; ++j) {
        const float* wb = wr + 40 + 8 * j;
        h2 p0 = h2{(_Float16)(wb[0] * sc), (_Float16)(wb[1] * sc)};
        h2 p1 = h2{(_Float16)(wb[2] * sc), (_Float16)(wb[3] * sc)};
        h2 p2 = h2{(_Float16)(wb[4] * sc), (_Float16)(wb[5] * sc)};
        h2 p3 = h2{(_Float16)(wb[6] * sc), (_Float16)(wb[7] * sc)};
        uint4 w4 = {__builtin_bit_cast(uint, p0), __builtin_bit_cast(uint, p1),
                    __builtin_bit_cast(uint, p2), __builtin_bit_cast(uint, p3)};
        *(uint4*)&wl[(i * 3 + j) * 256] = w4;
      }
    }
  }

  float hj0 = h0 ? h0[u0] : 0.f;
  float hj1 = h0 ? h0[u0 + 1] : 0.f;
  const float bhn0 = bhh[2 * HN + u0] * (2.f * L2E);
  const float bhn1 = bhh[2 * HN + u0 + 1] * (2.f * L2E);

  if (tid < 128) {
    float a = h0 ? h0[2 * tid] : 0.f;
    float b = h0 ? h0[2 * tid + 1] : 0.f;
    h2 pv = h2{(_Float16)a, (_Float16)b};
    hlds[(tid >> 5) * 40 + (tid & 31)] = __builtin_bit_cast(uint, pv);
  }
  __syncthreads();

  const int wadr = (q >> 5) * 40 + (q & 31);

  for (int t = 0; t < TT; ++t) {
    // This step's x-projection (issued early; lands during the matvec).
    float2 xr, xz, xn;
    {
      const float* xpt = xp + (size_t)t * H3 + u0;
      xr = *(const float2*)(xpt);
      xz = *(const float2*)(xpt + HN);
      xn = *(const float2*)(xpt + 2 * HN);
    }

    // Matvec part A: pairs 0..19 from register weights (120 fdot2).
    const uint* hb = &hlds[(t & 1) * 160 + kc * 40];
    float a[6] = {0.f, 0.f, 0.f, 0.f, 0.f, 0.f};
#pragma unroll
    for (int qq = 0; qq < 5; ++qq) {
      uint4 v = *(const uint4*)&hb[qq * 4];
      uint hv[4] = {v.x, v.y, v.z, v.w};
#pragma unroll
      for (int i = 0; i < 6; ++i)
#pragma unroll
        for (int p = 0; p < 4; ++p)
          a[i] = fdot2(wreg[i][qq * 4 + p], __builtin_bit_cast(h2, hv[p]), a[i]);
    }

    // Matvec part B: pairs 20..31 with weights streamed from LDS
    // (18 conflict-free ds_read_b128; issue on the LDS pipe).
#pragma unroll
    for (int j = 0; j < 3; ++j) {
      uint4 v = *(const uint4*)&hb[20 + j * 4];
      uint hv[4] = {v.x, v.y, v.z, v.w};
#pragma unroll
      for (int i = 0; i < 6; ++i) {
        uint4 w4 = *(const uint4*)&wl[(i * 3 + j) * 256];
        uint wv4[4] = {w4.x, w4.y, w4.z, w4.w};
#pragma unroll
        for (int p = 0; p < 4; ++p)
          a[i] = fdot2(__builtin_bit_cast(h2, wv4[p]),
                       __builtin_bit_cast(h2, hv[p]), a[i]);
      }
    }

    // Quad butterfly: all 4 lanes end with the full, bit-identical k-sum.
#pragma unroll
    for (int i = 0; i < 6; ++i) {
      float v = a[i];
      v += dpp_qperm<0xB1>(v);  // xor 1
      v += dpp_qperm<0x4E>(v);  // xor 2
      a[i] = v;
    }

    // Gates, fully local (args pre-scaled by log2e / 2log2e).
    float r0 = fast_rcp(1.f + fast_exp2(-(xr.x + a[0])));
    float z0 = fast_rcp(1.f + fast_exp2(-(xz.x + a[1])));
    float n0 = fmaf(2.f, fast_rcp(1.f + fast_exp2(-fmaf(r0, a[2] + bhn0, xn.x))), -1.f);
    hj0 = fmaf(z0, hj0 - n0, n0);
    float r1 = fast_rcp(1.f + fast_exp2(-(xr.y + a[3])));
    float z1 = fast_rcp(1.f + fast_exp2(-(xz.y + a[4])));
    float n1 = fmaf(2.f, fast_rcp(1.f + fast_exp2(-fmaf(r1, a[5] + bhn1, xn.y))), -1.f);
    hj1 = fmaf(z1, hj1 - n1, n1);

    h2 pv = h2{(_Float16)hj0, (_Float16)hj1};
    if (kc == 0) {
      hlds[((t & 1) ^ 1) * 160 + wadr] = __builtin_bit_cast(uint, pv);
      if (hs_out) *(float2*)&hs_out[(size_t)t * HN + u0] = make_float2(hj0, hj1);
    }
    __syncthreads();
  }
  if (hT_out && kc == 0) *(float2*)&hT_out[u0] = make_float2(hj0, hj1);
}

#define GRU_LDS_BYTES ((320 + 8 * 18 * 256) * 4)  // 148736 B

extern "C" void kernel_launch(void* const* d_in, const int* in_sizes, int n_in,
                              void* d_out, int out_size, void* d_ws, size_t ws_size,
                              hipStream_t stream) {
  const float* x     = (const float*)d_in[0];   // [1, 2048, 1739]
  const float* Wih_e = (const float*)d_in[2];   // [768, 1739]
  const float* Whh_e = (const float*)d_in[3];   // [768, 256]
  const float* bih_e = (const float*)d_in[4];   // [768]
  const float* bhh_e = (const float*)d_in[5];   // [768]
  const float* Wih_d = (const float*)d_in[6];
  const float* Whh_d = (const float*)d_in[7];
  const float* bih_d = (const float*)d_in[8];
  const float* bhh_d = (const float*)d_in[9];
  const float* Wout  = (const float*)d_in[10];  // [1739, 256]
  const float* bout  = (const float*)d_in[11];  // [1739]
  float* out = (float*)d_out;                   // [2048, 1, 1739]

  float* ws = (float*)d_ws;
  float* xpe  = ws;                              // 2048*768
  float* xpd  = xpe + (size_t)TT * H3;           // 2048*768
  float* hs   = xpd + (size_t)TT * H3;           // 2048*256
  float* henc = hs + (size_t)TT * HN;            // 256

  // Allow >64 KB dynamic LDS for the scan kernel (one-time host call;
  // safe under graph capture -- not a stream operation).
  static bool s_attr = false;
  if (!s_attr) {
    hipFuncSetAttribute((const void*)gru_seq,
                        hipFuncAttributeMaxDynamicSharedMemorySize,
                        GRU_LDS_BYTES);
    s_attr = true;
  }

  dim3 blk(256);
  // x-projections, pre-scaled for exp2-based gates:
  //   rows [0,512) (r,z): (x@W^T + bih + bhh) * log2e
  //   rows [512,768) (n): (x@W^T + bih) * 2log2e   (bhh n-part in-gate)
  gemm_abt<<<dim3(12, 32), blk, 0, stream>>>(x, TT, II, Wih_e, H3, bih_e, bhh_e, 2 * HN,
                                             L2E, 2.f * L2E, 2 * HN, xpe);
  gemm_abt<<<dim3(12, 32), blk, 0, stream>>>(x, TT, II, Wih_d, H3, bih_d, bhh_d, 2 * HN,
                                             L2E, 2.f * L2E, 2 * HN, xpd);
  // encoder scan -> henc
  gru_seq<<<1, 512, GRU_LDS_BYTES, stream>>>(xpe, Whh_e, bhh_e, nullptr, nullptr, henc);
  // decoder scan -> hs
  gru_seq<<<1, 512, GRU_LDS_BYTES, stream>>>(xpd, Whh_d, bhh_d, henc, hs, nullptr);
  // output projection (unscaled)
  gemm_abt<<<dim3(28, 32), blk, 0, stream>>>(hs, TT, HN, Wout, II, bout, nullptr, 0,
                                             1.f, 1.f, 0, out);
}